// Round 2
// baseline (56737.177 us; speedup 1.0000x reference)
//
#include <hip/hip_runtime.h>
#include <hip/hip_bf16.h>
#include <math.h>

#define V    50257
#define E    512
#define H    1024
#define S    128
#define BS   8
#define T    64
#define SOS  1
#define EOS  2
#define NEGV (-1e9f)
#define H3   (3*H)
#define NVT  50          // ceil(V/1024) vocab tiles for logits
#define TKCH 6283        // ceil(V/8) per-beam topk chunk

// ---------------- init ----------------
__global__ void k_init(const float* __restrict__ h0, float* h, float* cum,
                       int* len, int* fin, int* lat, int* tok) {
    int t = threadIdx.x;
    for (int i = t; i < BS*H; i += 256) h[i] = h0[i % H];
    for (int i = t; i < BS*T; i += 256) tok[i] = 0;
    if (t < BS) { cum[t] = 0.f; len[t] = 1; fin[t] = 0; lat[t] = SOS; }
}

// ---------------- GRU partials (split-K, deterministic) ----------------
// part[((k*4+g)*8 + b)*H + j], g: 0=z 1=r 2=n_x 3=n_h
__global__ __launch_bounds__(256) void k_gru_part(
    const float* __restrict__ emb, const float* __restrict__ Wx,
    const float* __restrict__ Wh, const float* __restrict__ h,
    const int* __restrict__ lat, float* __restrict__ part, int rpk)
{
    int jb = blockIdx.x;        // 0..3 (j block of 256)
    int k  = blockIdx.y;        // 0..ks-1
    int t  = threadIdx.x;
    int j  = jb*256 + t;
    int c0 = k * rpk;
    __shared__ float vals[192*8];   // max rpk=192
    for (int m = t; m < rpk*8; m += 256) {
        int c = c0 + (m >> 3);
        int b = m & 7;
        float v;
        if (c < E) v = emb[(size_t)lat[b]*E + c];
        else       v = h[b*H + (c - E)];
        vals[m] = v;
    }
    __syncthreads();
    float pz[BS] = {0}, pr[BS] = {0}, pnx[BS] = {0}, pnh[BS] = {0};
    for (int cc = 0; cc < rpk; ++cc) {
        int c = c0 + cc;
        bool isx = (c < E);
        const float* Wrow = isx ? (Wx + (size_t)c*H3) : (Wh + (size_t)(c-E)*H3);
        float wz = Wrow[j];
        float wr = Wrow[j + H];
        float wn = Wrow[j + 2*H];
        #pragma unroll
        for (int b = 0; b < BS; ++b) {
            float v = vals[cc*8 + b];
            pz[b] += v * wz;
            pr[b] += v * wr;
            if (isx) pnx[b] += v * wn; else pnh[b] += v * wn;
        }
    }
    #pragma unroll
    for (int b = 0; b < BS; ++b) {
        part[(((size_t)k*4 + 0)*8 + b)*H + j] = pz[b];
        part[(((size_t)k*4 + 1)*8 + b)*H + j] = pr[b];
        part[(((size_t)k*4 + 2)*8 + b)*H + j] = pnx[b];
        part[(((size_t)k*4 + 3)*8 + b)*H + j] = pnh[b];
    }
}

// ---------------- fused: gate reduce + attention (one block per beam) ----------------
__global__ __launch_bounds__(256) void k_gate_attn(
    const float* __restrict__ part, const float* __restrict__ h,
    const float* __restrict__ enc, float* __restrict__ hcT, int ks)
{
    int b = blockIdx.x;
    int t = threadIdx.x;
    __shared__ float hn[H];
    __shared__ float att[S];
    __shared__ float smax, ssum;
    for (int j = t; j < H; j += 256) {
        float pz = 0.f, pr = 0.f, pnx = 0.f, pnh = 0.f;
        for (int k = 0; k < ks; ++k) {
            pz  += part[(((size_t)k*4 + 0)*8 + b)*H + j];
            pr  += part[(((size_t)k*4 + 1)*8 + b)*H + j];
            pnx += part[(((size_t)k*4 + 2)*8 + b)*H + j];
            pnh += part[(((size_t)k*4 + 3)*8 + b)*H + j];
        }
        float z = 1.f / (1.f + expf(-pz));
        float r = 1.f / (1.f + expf(-pr));
        float n = tanhf(pnx + r * pnh);
        float v = (1.f - z) * n + z * h[b*H + j];
        hn[j] = v;
        hcT[(size_t)j*8 + b] = v;
    }
    __syncthreads();
    int wave = t >> 6, lane = t & 63;
    for (int s = wave; s < S; s += 4) {
        float acc = 0.f;
        for (int hh = lane; hh < H; hh += 64)
            acc += hn[hh] * enc[(size_t)s*H + hh];
        #pragma unroll
        for (int off = 32; off; off >>= 1) acc += __shfl_down(acc, off, 64);
        if (lane == 0) att[s] = acc;
    }
    __syncthreads();
    if (t == 0) {
        float m = -3.0e38f;
        for (int s = 0; s < S; ++s) m = fmaxf(m, att[s]);
        smax = m;
    }
    __syncthreads();
    if (t < S) att[t] = expf(att[t] - smax);
    __syncthreads();
    if (t == 0) {
        float sum = 0.f;
        for (int s = 0; s < S; ++s) sum += att[s];
        ssum = sum;
    }
    __syncthreads();
    if (t < S) att[t] = att[t] / ssum;
    __syncthreads();
    for (int j = t; j < H; j += 256) {
        float acc = 0.f;
        for (int s = 0; s < S; ++s) acc += att[s] * enc[(size_t)s*H + j];
        hcT[(size_t)(H + j)*8 + b] = acc;
    }
}

// ---------------- big GEMV partials: lpart[r][b][v] over row chunk r ----------------
// grid (NVT, rch); each thread owns 4 consecutive vocab cols, float4 W loads.
__global__ __launch_bounds__(256) void k_logits_part(
    const float* __restrict__ Wout, const float* __restrict__ hcT,
    float* __restrict__ lpart, int rowsPerChunk)
{
    int t = threadIdx.x;
    int v = blockIdx.x * 1024 + t * 4;
    int nc = (v < V) ? ((V - v < 4) ? (V - v) : 4) : 0;
    int r0base = blockIdx.y * rowsPerChunk;
    __shared__ float tile[256*8];
    float4 acc[BS];
    #pragma unroll
    for (int b = 0; b < BS; ++b) acc[b] = make_float4(0.f, 0.f, 0.f, 0.f);

    for (int r0 = r0base; r0 < r0base + rowsPerChunk; r0 += 256) {
        __syncthreads();
        for (int m = t; m < 256*8; m += 256)
            tile[m] = hcT[(size_t)r0*8 + m];
        __syncthreads();
        if (nc == 4) {
            for (int ii = 0; ii < 256; ++ii) {
                float4 w = *(const float4*)(Wout + (size_t)(r0+ii)*V + v);
                float4 a0 = *(const float4*)(tile + ii*8);
                float4 a1 = *(const float4*)(tile + ii*8 + 4);
                acc[0].x += a0.x*w.x; acc[0].y += a0.x*w.y; acc[0].z += a0.x*w.z; acc[0].w += a0.x*w.w;
                acc[1].x += a0.y*w.x; acc[1].y += a0.y*w.y; acc[1].z += a0.y*w.z; acc[1].w += a0.y*w.w;
                acc[2].x += a0.z*w.x; acc[2].y += a0.z*w.y; acc[2].z += a0.z*w.z; acc[2].w += a0.z*w.w;
                acc[3].x += a0.w*w.x; acc[3].y += a0.w*w.y; acc[3].z += a0.w*w.z; acc[3].w += a0.w*w.w;
                acc[4].x += a1.x*w.x; acc[4].y += a1.x*w.y; acc[4].z += a1.x*w.z; acc[4].w += a1.x*w.w;
                acc[5].x += a1.y*w.x; acc[5].y += a1.y*w.y; acc[5].z += a1.y*w.z; acc[5].w += a1.y*w.w;
                acc[6].x += a1.z*w.x; acc[6].y += a1.z*w.y; acc[6].z += a1.z*w.z; acc[6].w += a1.z*w.w;
                acc[7].x += a1.w*w.x; acc[7].y += a1.w*w.y; acc[7].z += a1.w*w.z; acc[7].w += a1.w*w.w;
            }
        } else if (nc > 0) {
            for (int ii = 0; ii < 256; ++ii) {
                for (int c = 0; c < nc; ++c) {
                    float wv = Wout[(size_t)(r0+ii)*V + v + c];
                    #pragma unroll
                    for (int b = 0; b < BS; ++b) {
                        float a = tile[ii*8 + b];
                        float* ac = (float*)&acc[b];
                        ac[c] += a * wv;
                    }
                }
            }
        }
    }
    if (nc == 4) {
        #pragma unroll
        for (int b = 0; b < BS; ++b)
            *(float4*)(lpart + ((size_t)blockIdx.y*8 + b)*V + v) = acc[b];
    } else if (nc > 0) {
        for (int b = 0; b < BS; ++b) {
            const float* ac = (const float*)&acc[b];
            for (int c = 0; c < nc; ++c)
                lpart[((size_t)blockIdx.y*8 + b)*V + v + c] = ac[c];
        }
    }
}

// ---------------- per-beam-per-chunk top-8 + logsumexp partial ----------------
// grid (BS beams, 8 chunks). Reduces lpart over r inline (fixed order, deterministic).
__global__ __launch_bounds__(256) void k_topk_part(
    const float* __restrict__ lpart, const float* __restrict__ bout,
    float* __restrict__ cand_v, int* __restrict__ cand_i,
    float* __restrict__ cm, int rch, float* __restrict__ cl)
{
    int b = blockIdx.x, c = blockIdx.y, t = threadIdx.x;
    int vstart = c * TKCH;
    int vend = (vstart + TKCH < V) ? (vstart + TKCH) : V;
    float bv[8]; int bi[8];
    #pragma unroll
    for (int r = 0; r < 8; ++r) { bv[r] = -3.0e38f; bi[r] = 0x7fffffff; }
    float m = -3.0e38f, l = 0.f;
    for (int v = vstart + t; v < vend; v += 256) {
        float x = bout[v];
        for (int r = 0; r < rch; ++r)
            x += lpart[((size_t)r*8 + b)*V + v];
        if (x > m) { l = l * expf(m - x) + 1.f; m = x; }
        else         l += expf(x - m);
        if (x > bv[7]) {
            bv[7] = x; bi[7] = v;
            #pragma unroll
            for (int q = 7; q > 0; --q) {
                if (bv[q] > bv[q-1]) {
                    float tv = bv[q]; bv[q] = bv[q-1]; bv[q-1] = tv;
                    int   ti = bi[q]; bi[q] = bi[q-1]; bi[q-1] = ti;
                }
            }
        }
    }
    __shared__ float pm[256], pl[256];
    pm[t] = m; pl[t] = l;
    __syncthreads();
    for (int off = 128; off; off >>= 1) {
        if (t < off) {
            float m2 = pm[t+off], l2 = pl[t+off];
            float M = fmaxf(pm[t], m2);
            pl[t] = pl[t]*expf(pm[t]-M) + l2*expf(m2-M);
            pm[t] = M;
        }
        __syncthreads();
    }
    if (t == 0) { cm[b*8 + c] = pm[0]; cl[b*8 + c] = pl[0]; }

    __shared__ float pv[2048];
    __shared__ int   pi[2048];
    __shared__ float rv[256];
    __shared__ int   ri[256], rp[256];
    #pragma unroll
    for (int r = 0; r < 8; ++r) { pv[t*8+r] = bv[r]; pi[t*8+r] = bi[r]; }
    __syncthreads();
    for (int round = 0; round < 8; ++round) {
        float lv = -3.0e38f; int li = 0x7fffffff, lp = -1;
        #pragma unroll
        for (int r = 0; r < 8; ++r) {
            float v2 = pv[t*8+r]; int i2 = pi[t*8+r];
            if (v2 > lv || (v2 == lv && i2 < li)) { lv = v2; li = i2; lp = t*8+r; }
        }
        rv[t] = lv; ri[t] = li; rp[t] = lp;
        __syncthreads();
        for (int off = 128; off; off >>= 1) {
            if (t < off) {
                if (rv[t+off] > rv[t] || (rv[t+off] == rv[t] && ri[t+off] < ri[t])) {
                    rv[t] = rv[t+off]; ri[t] = ri[t+off]; rp[t] = rp[t+off];
                }
            }
            __syncthreads();
        }
        if (t == 0) {
            cand_v[(b*8 + c)*8 + round] = rv[0];
            cand_i[(b*8 + c)*8 + round] = ri[0];
            pv[rp[0]] = -3.0e38f; pi[rp[0]] = 0x7fffffff;
        }
        __syncthreads();
    }
}

// ---------------- merge chunks + beam update (exact reference semantics) ----------------
__global__ __launch_bounds__(256) void k_merge_update(
    const float* __restrict__ cand_v, const int* __restrict__ cand_i,
    const float* __restrict__ cm, const float* __restrict__ cl,
    const float* cum_i, const int* len_i, const int* fin_i,
    const int* lat_i, const int* tok_i,
    float* cum_o, int* len_o, int* fin_o, int* lat_o, int* tok_o,
    const float* __restrict__ hcT, float* __restrict__ h, int step)
{
    int t = threadIdx.x;
    __shared__ float t8v[64];
    __shared__ int   t8i[64];
    __shared__ float lse[8];
    if (t < 8) {
        int b = t;
        // merge logsumexp partials (fixed chunk order)
        float m = -3.0e38f, l = 0.f;
        for (int c = 0; c < 8; ++c) {
            float m2 = cm[b*8 + c], l2 = cl[b*8 + c];
            float M = fmaxf(m, m2);
            l = l*expf(m - M) + l2*expf(m2 - M);
            m = M;
        }
        lse[b] = m + logf(l);
        // merge 64 candidates -> global top 8 (value desc, index asc tie-break)
        bool taken[64];
        for (int i = 0; i < 64; ++i) taken[i] = false;
        for (int round = 0; round < 8; ++round) {
            float bvv = -3.4e38f; int bii = 0x7fffffff, bp = 0;
            for (int i = 0; i < 64; ++i) {
                if (taken[i]) continue;
                float v2 = cand_v[b*64 + i]; int i2 = cand_i[b*64 + i];
                if (v2 > bvv || (v2 == bvv && i2 < bii)) { bvv = v2; bii = i2; bp = i; }
            }
            taken[bp] = true;
            t8v[b*8 + round] = bvv;
            t8i[b*8 + round] = bii;
        }
    }
    __syncthreads();

    __shared__ float flat[64];
    __shared__ float ccum[64];
    __shared__ int   clen[64];
    __shared__ int   sel[8];
    if (t < 64) {
        int b = t >> 3, j = t & 7;
        int alive = fin_i[b] ? 0 : 1;
        float lp = t8v[b*8 + j] - lse[b];
        float cc = cum_i[b] + (alive ? lp : 0.f);
        int   cln = len_i[b] + alive;
        float score = cc / (float)cln;
        bool valid = (alive || j == 0) && ((step > 0) || (b == 0));
        flat[t] = valid ? score : NEGV;
        ccum[t] = cc; clen[t] = cln;
    }
    __syncthreads();
    if (t == 0) {
        bool taken[64];
        for (int i = 0; i < 64; ++i) taken[i] = false;
        for (int r = 0; r < 8; ++r) {
            float bestv = -3.4e38f; int bidx = 0;
            for (int i = 0; i < 64; ++i) {
                if (!taken[i] && flat[i] > bestv) { bestv = flat[i]; bidx = i; }
            }
            taken[bidx] = true; sel[r] = bidx;
        }
    }
    __syncthreads();
    if (t < 8) {
        int idx = sel[t];
        int parent = idx >> 3, child = idx & 7;
        int p_fin = fin_i[parent];
        int new_tok = t8i[parent*8 + child];
        cum_o[t] = ccum[idx];
        len_o[t] = clen[idx];
        fin_o[t] = (p_fin || new_tok == EOS) ? 1 : 0;
        lat_o[t] = p_fin ? lat_i[parent] : new_tok;
    }
    __syncthreads();
    for (int m = t; m < BS*T; m += 256) {
        int nb = m / T, pos = m % T;
        int idx = sel[nb];
        int parent = idx >> 3, child = idx & 7;
        int p_fin = fin_i[parent];
        int p_len = len_i[parent];
        int new_tok = t8i[parent*8 + child];
        int val = tok_i[parent*T + pos];
        if (pos == p_len - 1 && !p_fin) val = new_tok;
        tok_o[m] = val;
    }
    for (int m = t; m < BS*H; m += 256) {
        int nb = m / H, j = m % H;
        int parent = sel[nb] >> 3;
        h[m] = hcT[(size_t)j*8 + parent];
    }
}

// ---------------- finalize ----------------
__global__ void k_final(const float* cum, const int* len, const int* fin,
                        const int* tok, float* out)
{
    int t = threadIdx.x;
    __shared__ int bestIdx;
    if (t == 0) {
        bool anyf = false;
        for (int b = 0; b < BS; ++b) anyf = anyf || (fin[b] != 0);
        float bestv = -3.4e38f; int bi_ = 0;
        for (int b = 0; b < BS; ++b) {
            float sc = cum[b] / (float)len[b];
            float adj = anyf ? (fin[b] ? sc : NEGV) : sc;
            if (adj > bestv) { bestv = adj; bi_ = b; }
        }
        bestIdx = bi_;
        out[T] = cum[bi_] / (float)len[bi_];
    }
    __syncthreads();
    if (t < T) out[t] = (float)tok[bestIdx*T + t];
}

extern "C" void kernel_launch(void* const* d_in, const int* in_sizes, int n_in,
                              void* d_out, int out_size, void* d_ws, size_t ws_size,
                              hipStream_t stream) {
    const float* emb  = (const float*)d_in[0];
    const float* Wx   = (const float*)d_in[1];
    const float* Wh   = (const float*)d_in[2];
    const float* Wout = (const float*)d_in[3];
    const float* bout = (const float*)d_in[4];
    const float* enc  = (const float*)d_in[5];
    const float* h0   = (const float*)d_in[6];
    float* out = (float*)d_out;

    // config: wide split (better BW) if workspace allows, else frugal fallback
    int KS, RCH;
    if (ws_size >= 24u*1024u*1024u) { KS = 32; RCH = 8; }
    else                            { KS = 8;  RCH = 1; }

    char* w = (char*)d_ws;
    auto alloc = [&](size_t bytes) -> char* {
        char* p = w; w += (bytes + 255) & ~(size_t)255; return p;
    };
    float* h      = (float*)alloc((size_t)BS*H*4);
    float* hcT    = (float*)alloc((size_t)2*H*BS*4);
    float* part   = (float*)alloc((size_t)KS*4*BS*H*4);
    float* lpart  = (float*)alloc((size_t)RCH*BS*V*4);
    float* cand_v = (float*)alloc(8*8*8*4);
    int*   cand_i = (int*)  alloc(8*8*8*4);
    float* cm     = (float*)alloc(64*4);
    float* cl     = (float*)alloc(64*4);
    float* cumb0  = (float*)alloc(8*4);
    float* cumb1  = (float*)alloc(8*4);
    int* lenb0 = (int*)alloc(8*4);
    int* lenb1 = (int*)alloc(8*4);
    int* finb0 = (int*)alloc(8*4);
    int* finb1 = (int*)alloc(8*4);
    int* latb0 = (int*)alloc(8*4);
    int* latb1 = (int*)alloc(8*4);
    int* tokb0 = (int*)alloc((size_t)BS*T*4);
    int* tokb1 = (int*)alloc((size_t)BS*T*4);

    float* cumb[2] = {cumb0, cumb1};
    int*   lenb[2] = {lenb0, lenb1};
    int*   finb[2] = {finb0, finb1};
    int*   latb[2] = {latb0, latb1};
    int*   tokb[2] = {tokb0, tokb1};

    k_init<<<1, 256, 0, stream>>>(h0, h, cumb[0], lenb[0], finb[0], latb[0], tokb[0]);

    int rpk = (E + H) / KS;
    int rowsPerChunk = 2*H / RCH;
    for (int s = 0; s < T; ++s) {
        int p = s & 1, q = 1 - p;
        k_gru_part<<<dim3(4, KS), 256, 0, stream>>>(emb, Wx, Wh, h, latb[p], part, rpk);
        k_gate_attn<<<BS, 256, 0, stream>>>(part, h, enc, hcT, KS);
        k_logits_part<<<dim3(NVT, RCH), 256, 0, stream>>>(Wout, hcT, lpart, rowsPerChunk);
        k_topk_part<<<dim3(BS, 8), 256, 0, stream>>>(lpart, bout, cand_v, cand_i, cm, RCH, cl);
        k_merge_update<<<1, 256, 0, stream>>>(cand_v, cand_i, cm, cl,
                                              cumb[p], lenb[p], finb[p], latb[p], tokb[p],
                                              cumb[q], lenb[q], finb[q], latb[q], tokb[q],
                                              hcT, h, s);
    }
    k_final<<<1, 64, 0, stream>>>(cumb[0], lenb[0], finb[0], tokb[0], out);
}

// Round 3
// 30371.921 us; speedup vs baseline: 1.8681x; 1.8681x over previous
//
#include <hip/hip_runtime.h>
#include <math.h>

#define V    50257
#define VP   50264      // bf16 copy pitch (mult of 8, even -> aligned ushort2)
#define E    512
#define H    1024
#define S    128
#define BS   8
#define T    64
#define SOS  1
#define EOS  2
#define NEGV (-1e9f)
#define H3   (3*H)
#define KS   16
#define RPK  ((E+H)/KS)   // 96
#define NSB  99           // screening blocks (99*512 >= V)
#define SCB  512          // cols per screening block
#define NC24 (NSB*24)     // 2376 candidates per beam

// ---------------- init ----------------
__global__ void k_init(const float* __restrict__ h0, float* h, float* cum,
                       int* len, int* fin, int* lat, int* tok) {
    int t = threadIdx.x;
    for (int i = t; i < BS*H; i += 256) h[i] = h0[i % H];
    for (int i = t; i < BS*T; i += 256) tok[i] = 0;
    if (t < BS) { cum[t] = 0.f; len[t] = 1; fin[t] = 0; lat[t] = SOS; }
}

// ---------------- one-time: Wout fp32 -> bf16 (RNE), padded pitch ----------------
__global__ __launch_bounds__(256) void k_cast(const float* __restrict__ Wout,
                                              unsigned short* __restrict__ Wb) {
    int r = blockIdx.x;                       // 0..2047
    const float* src = Wout + (size_t)r * V;
    unsigned short* dst = Wb + (size_t)r * VP;
    for (int c = threadIdx.x; c < VP; c += 256) {
        float f = (c < V) ? src[c] : 0.f;
        unsigned int u = __float_as_uint(f);
        unsigned int rnd = ((u >> 16) & 1u) + 0x7FFFu;
        dst[c] = (unsigned short)((u + rnd) >> 16);
    }
}

// ---------------- GRU partials (split-K, deterministic) ----------------
__global__ __launch_bounds__(256) void k_gru_part(
    const float* __restrict__ emb, const float* __restrict__ Wx,
    const float* __restrict__ Wh, const float* __restrict__ h,
    const int* __restrict__ lat, float* __restrict__ part)
{
    int jb = blockIdx.x;        // 0..3
    int k  = blockIdx.y;        // 0..KS-1
    int t  = threadIdx.x;
    int j  = jb*256 + t;
    int c0 = k * RPK;
    __shared__ float vals[RPK*BS];
    for (int m = t; m < RPK*8; m += 256) {
        int c = c0 + (m >> 3);
        int b = m & 7;
        float v;
        if (c < E) v = emb[(size_t)lat[b]*E + c];
        else       v = h[b*H + (c - E)];
        vals[m] = v;
    }
    __syncthreads();
    float pz[BS] = {0}, pr[BS] = {0}, pnx[BS] = {0}, pnh[BS] = {0};
    for (int cc = 0; cc < RPK; ++cc) {
        int c = c0 + cc;
        bool isx = (c < E);
        const float* Wrow = isx ? (Wx + (size_t)c*H3) : (Wh + (size_t)(c-E)*H3);
        float wz = Wrow[j];
        float wr = Wrow[j + H];
        float wn = Wrow[j + 2*H];
        #pragma unroll
        for (int b = 0; b < BS; ++b) {
            float v = vals[cc*8 + b];
            pz[b] += v * wz;
            pr[b] += v * wr;
            if (isx) pnx[b] += v * wn; else pnh[b] += v * wn;
        }
    }
    #pragma unroll
    for (int b = 0; b < BS; ++b) {
        part[(((size_t)k*4 + 0)*8 + b)*H + j] = pz[b];
        part[(((size_t)k*4 + 1)*8 + b)*H + j] = pr[b];
        part[(((size_t)k*4 + 2)*8 + b)*H + j] = pnx[b];
        part[(((size_t)k*4 + 3)*8 + b)*H + j] = pnh[b];
    }
}

// ---------------- fused: gate reduce + attention (one block per beam) ----------------
__global__ __launch_bounds__(256) void k_gate_attn(
    const float* __restrict__ part, const float* __restrict__ h,
    const float* __restrict__ enc, float* __restrict__ hcT)
{
    int b = blockIdx.x;
    int t = threadIdx.x;
    __shared__ float hn[H];
    __shared__ float att[S];
    __shared__ float smax, ssum;
    for (int j = t; j < H; j += 256) {
        float pz = 0.f, pr = 0.f, pnx = 0.f, pnh = 0.f;
        #pragma unroll
        for (int k = 0; k < KS; ++k) {
            pz  += part[(((size_t)k*4 + 0)*8 + b)*H + j];
            pr  += part[(((size_t)k*4 + 1)*8 + b)*H + j];
            pnx += part[(((size_t)k*4 + 2)*8 + b)*H + j];
            pnh += part[(((size_t)k*4 + 3)*8 + b)*H + j];
        }
        float z = 1.f / (1.f + expf(-pz));
        float r = 1.f / (1.f + expf(-pr));
        float n = tanhf(pnx + r * pnh);
        float v = (1.f - z) * n + z * h[b*H + j];
        hn[j] = v;
        hcT[(size_t)j*8 + b] = v;
    }
    __syncthreads();
    int wave = t >> 6, lane = t & 63;
    for (int s = wave; s < S; s += 4) {
        float acc = 0.f;
        #pragma unroll 4
        for (int hh = lane; hh < H; hh += 64)
            acc += hn[hh] * enc[(size_t)s*H + hh];
        #pragma unroll
        for (int off = 32; off; off >>= 1) acc += __shfl_down(acc, off, 64);
        if (lane == 0) att[s] = acc;
    }
    __syncthreads();
    if (t == 0) {
        float m = -3.0e38f;
        for (int s = 0; s < S; ++s) m = fmaxf(m, att[s]);
        smax = m;
    }
    __syncthreads();
    if (t < S) att[t] = expf(att[t] - smax);
    __syncthreads();
    if (t == 0) {
        float sum = 0.f;
        for (int s = 0; s < S; ++s) sum += att[s];
        ssum = sum;
    }
    __syncthreads();
    if (t < S) att[t] = att[t] / ssum;
    __syncthreads();
    for (int j = t; j < H; j += 256) {
        float acc = 0.f;
        for (int s = 0; s < S; ++s) acc += att[s] * enc[(size_t)s*H + j];
        hcT[(size_t)(H + j)*8 + b] = acc;
    }
}

// ---------------- bf16 screening GEMV + per-block per-beam top-24 + lse partials ----------------
__global__ __launch_bounds__(256) void k_screen(
    const unsigned short* __restrict__ Wb, const float* __restrict__ bout,
    const float* __restrict__ hcT,
    float* __restrict__ candV, int* __restrict__ candI,
    float* __restrict__ candM, float* __restrict__ candL)
{
    __shared__ float hc[2048*8];     // 64 KiB
    __shared__ float lg[8][SCB];     // 16 KiB
    int t = threadIdx.x;
    int blk = blockIdx.x;
    int v0 = blk * SCB;
    for (int m = t; m < 2048*8; m += 256) hc[m] = hcT[m];
    __syncthreads();

    int c = v0 + 2*t;
    int cl = (c <= VP-2) ? c : (VP-2);     // clamp (tail garbage discarded below)
    const unsigned short* wp = Wb + cl;
    float a0[8] = {0,0,0,0,0,0,0,0};
    float a1[8] = {0,0,0,0,0,0,0,0};
    #pragma unroll 16
    for (int r = 0; r < 2048; ++r) {
        unsigned int w2 = *(const unsigned int*)(wp + (size_t)r * VP);
        float w0 = __uint_as_float(w2 << 16);
        float w1 = __uint_as_float(w2 & 0xFFFF0000u);
        const float* hr = hc + r*8;
        #pragma unroll
        for (int b = 0; b < 8; ++b) { a0[b] += hr[b]*w0; a1[b] += hr[b]*w1; }
    }
    bool ok0 = (c < V), ok1 = (c+1 < V);
    float b0 = ok0 ? bout[c]   : 0.f;
    float b1 = ok1 ? bout[c+1] : 0.f;
    #pragma unroll
    for (int b = 0; b < 8; ++b) {
        lg[b][2*t]   = ok0 ? (a0[b] + b0) : -3.0e38f;
        lg[b][2*t+1] = ok1 ? (a1[b] + b1) : -3.0e38f;
    }
    __syncthreads();

    int wv = t >> 6, ln = t & 63;
    for (int bi2 = 0; bi2 < 2; ++bi2) {
        int b = wv + bi2*4;
        // lane-local sorted top-8 over its 8 values (idx ascending -> strict > keeps lower idx on ties)
        float sv[8]; int si[8];
        #pragma unroll
        for (int q = 0; q < 8; ++q) { sv[q] = -3.0e38f; si[q] = 0x7fffffff; }
        float m = -3.0e38f, l = 0.f;
        #pragma unroll
        for (int kk = 0; kk < 8; ++kk) {
            float x = lg[b][ln*8 + kk];
            int  ix = v0 + ln*8 + kk;
            if (x > m) { l = l * expf(m - x) + 1.f; m = x; }
            else         l += expf(x - m);
            if (x > sv[7]) {
                sv[7] = x; si[7] = ix;
                #pragma unroll
                for (int q = 7; q > 0; --q) {
                    if (sv[q] > sv[q-1]) {
                        float tv = sv[q]; sv[q] = sv[q-1]; sv[q-1] = tv;
                        int   ti = si[q]; si[q] = si[q-1]; si[q-1] = ti;
                    }
                }
            }
        }
        // wave-merge lse partial (butterfly -> all lanes same)
        #pragma unroll
        for (int off = 1; off < 64; off <<= 1) {
            float m2 = __shfl_xor(m, off, 64);
            float l2 = __shfl_xor(l, off, 64);
            float M = fmaxf(m, m2);
            l = l*expf(m - M) + l2*expf(m2 - M);
            m = M;
        }
        if (ln == 0) { candM[b*NSB + blk] = m; candL[b*NSB + blk] = l; }
        // 24 rounds of wave argmax-with-pop
        int ptr = 0;
        for (int round = 0; round < 24; ++round) {
            float hv = (ptr < 8) ? sv[ptr] : -3.0e38f;
            int   hi = (ptr < 8) ? si[ptr] : 0x7fffffff;
            float bv = hv; int bix = hi; int bl = ln;
            #pragma unroll
            for (int off = 1; off < 64; off <<= 1) {
                float ov = __shfl_xor(bv, off, 64);
                int   oi = __shfl_xor(bix, off, 64);
                int   ol = __shfl_xor(bl, off, 64);
                if (ov > bv || (ov == bv && oi < bix)) { bv = ov; bix = oi; bl = ol; }
            }
            if (ln == bl) ptr++;
            if (ln == 0) {
                candV[((size_t)b*NSB + blk)*24 + round] = bv;
                candI[((size_t)b*NSB + blk)*24 + round] = bix;
            }
        }
    }
}

// ---------------- per-beam: merge 99x24 -> global top-24 + merge lse ----------------
__global__ __launch_bounds__(64) void k_merge24(
    const float* __restrict__ candV, const int* __restrict__ candI,
    const float* __restrict__ candM, const float* __restrict__ candL,
    int* __restrict__ top24i, float* __restrict__ lse8)
{
    int b = blockIdx.x, ln = threadIdx.x;
    __shared__ float v[NC24];
    __shared__ int   id[NC24];
    for (int i = ln; i < NC24; i += 64) {
        v[i]  = candV[(size_t)b*NC24 + i];
        id[i] = candI[(size_t)b*NC24 + i];
    }
    __syncthreads();
    for (int round = 0; round < 24; ++round) {
        float bv = -3.4e38f; int bix = 0x7fffffff; int bp = 0;
        for (int i = ln; i < NC24; i += 64) {
            float vv = v[i]; int ii = id[i];
            if (vv > bv || (vv == bv && ii < bix)) { bv = vv; bix = ii; bp = i; }
        }
        int bl = ln;
        #pragma unroll
        for (int off = 1; off < 64; off <<= 1) {
            float ov = __shfl_xor(bv, off, 64);
            int   oi = __shfl_xor(bix, off, 64);
            int   ol = __shfl_xor(bl, off, 64);
            if (ov > bv || (ov == bv && oi < bix)) { bv = ov; bix = oi; bl = ol; }
        }
        if (ln == 0) top24i[b*24 + round] = bix;
        if (ln == bl) { v[bp] = -3.4e38f; id[bp] = 0x7fffffff; }
        __syncthreads();
    }
    if (ln == 0) {
        float m = -3.0e38f, l = 0.f;
        for (int c = 0; c < NSB; ++c) {
            float m2 = candM[b*NSB + c], l2 = candL[b*NSB + c];
            float M = fmaxf(m, m2);
            l = l*expf(m - M) + l2*expf(m2 - M);
            m = M;
        }
        lse8[b] = m + logf(l);
    }
}

// ---------------- exact fp32 rescore of the 8x24 candidate columns ----------------
__global__ __launch_bounds__(256) void k_rescore(
    const float* __restrict__ Wout, const float* __restrict__ bout,
    const float* __restrict__ hcT, const int* __restrict__ top24i,
    float* __restrict__ exV)
{
    int b = blockIdx.x, cnd = blockIdx.y, t = threadIdx.x;
    int col = top24i[b*24 + cnd];
    float acc = 0.f;
    #pragma unroll
    for (int k = 0; k < 8; ++k) {
        int r = t + k*256;
        acc += Wout[(size_t)r*V + col] * hcT[(size_t)r*8 + b];
    }
    __shared__ float red[256];
    red[t] = acc;
    __syncthreads();
    for (int off = 128; off; off >>= 1) {
        if (t < off) red[t] += red[t + off];
        __syncthreads();
    }
    if (t == 0) exV[b*24 + cnd] = red[0] + bout[col];
}

// ---------------- beam update from exact candidates (reference semantics) ----------------
__global__ __launch_bounds__(256) void k_update(
    const float* __restrict__ exV, const int* __restrict__ top24i,
    const float* __restrict__ lse8,
    const float* cum_i, const int* len_i, const int* fin_i,
    const int* lat_i, const int* tok_i,
    float* cum_o, int* len_o, int* fin_o, int* lat_o, int* tok_o,
    const float* __restrict__ hcT, float* __restrict__ h, int step)
{
    int t = threadIdx.x;
    __shared__ float t8v[64];
    __shared__ int   t8i[64];
    if (t < 8) {
        int b = t;
        bool taken[24];
        for (int i = 0; i < 24; ++i) taken[i] = false;
        for (int r = 0; r < 8; ++r) {
            float bv = -3.4e38f; int bix = 0x7fffffff, bp = 0;
            for (int i = 0; i < 24; ++i) {
                if (taken[i]) continue;
                float vv = exV[b*24 + i]; int ii = top24i[b*24 + i];
                if (vv > bv || (vv == bv && ii < bix)) { bv = vv; bix = ii; bp = i; }
            }
            taken[bp] = true;
            t8v[b*8 + r] = bv;
            t8i[b*8 + r] = bix;
        }
    }
    __syncthreads();

    __shared__ float flat[64];
    __shared__ float ccum[64];
    __shared__ int   clen[64];
    __shared__ int   sel[8];
    if (t < 64) {
        int b = t >> 3, j = t & 7;
        int alive = fin_i[b] ? 0 : 1;
        float lp = t8v[b*8 + j] - lse8[b];
        float cc = cum_i[b] + (alive ? lp : 0.f);
        int   cln = len_i[b] + alive;
        float score = cc / (float)cln;
        bool valid = (alive || j == 0) && ((step > 0) || (b == 0));
        flat[t] = valid ? score : NEGV;
        ccum[t] = cc; clen[t] = cln;
    }
    __syncthreads();
    if (t == 0) {
        bool taken[64];
        for (int i = 0; i < 64; ++i) taken[i] = false;
        for (int r = 0; r < 8; ++r) {
            float bestv = -3.4e38f; int bidx = 0;
            for (int i = 0; i < 64; ++i) {
                if (!taken[i] && flat[i] > bestv) { bestv = flat[i]; bidx = i; }
            }
            taken[bidx] = true; sel[r] = bidx;
        }
    }
    __syncthreads();
    if (t < 8) {
        int idx = sel[t];
        int parent = idx >> 3, child = idx & 7;
        int p_fin = fin_i[parent];
        int new_tok = t8i[parent*8 + child];
        cum_o[t] = ccum[idx];
        len_o[t] = clen[idx];
        fin_o[t] = (p_fin || new_tok == EOS) ? 1 : 0;
        lat_o[t] = p_fin ? lat_i[parent] : new_tok;
    }
    __syncthreads();
    for (int m = t; m < BS*T; m += 256) {
        int nb = m / T, pos = m % T;
        int idx = sel[nb];
        int parent = idx >> 3, child = idx & 7;
        int p_fin = fin_i[parent];
        int p_len = len_i[parent];
        int new_tok = t8i[parent*8 + child];
        int val = tok_i[parent*T + pos];
        if (pos == p_len - 1 && !p_fin) val = new_tok;
        tok_o[m] = val;
    }
    for (int m = t; m < BS*H; m += 256) {
        int nb = m / H, j = m % H;
        int parent = sel[nb] >> 3;
        h[m] = hcT[(size_t)j*8 + parent];
    }
}

// ================= fallback path (validated R2 structure, fp32) =================
__global__ __launch_bounds__(256) void k_logits_part(
    const float* __restrict__ Wout, const float* __restrict__ hcT,
    float* __restrict__ lpart)
{
    int t = threadIdx.x;
    int v = blockIdx.x * 1024 + t * 4;
    int nc = (v < V) ? ((V - v < 4) ? (V - v) : 4) : 0;
    int r0 = blockIdx.y * 256;
    __shared__ float tile[256*8];
    float4 acc[BS];
    #pragma unroll
    for (int b = 0; b < BS; ++b) acc[b] = make_float4(0.f,0.f,0.f,0.f);
    for (int m = t; m < 256*8; m += 256) tile[m] = hcT[(size_t)r0*8 + m];
    __syncthreads();
    if (nc == 4) {
        for (int ii = 0; ii < 256; ++ii) {
            float4 w = *(const float4*)(Wout + (size_t)(r0+ii)*V + v);
            float4 a0 = *(const float4*)(tile + ii*8);
            float4 a1 = *(const float4*)(tile + ii*8 + 4);
            acc[0].x += a0.x*w.x; acc[0].y += a0.x*w.y; acc[0].z += a0.x*w.z; acc[0].w += a0.x*w.w;
            acc[1].x += a0.y*w.x; acc[1].y += a0.y*w.y; acc[1].z += a0.y*w.z; acc[1].w += a0.y*w.w;
            acc[2].x += a0.z*w.x; acc[2].y += a0.z*w.y; acc[2].z += a0.z*w.z; acc[2].w += a0.z*w.w;
            acc[3].x += a0.w*w.x; acc[3].y += a0.w*w.y; acc[3].z += a0.w*w.z; acc[3].w += a0.w*w.w;
            acc[4].x += a1.x*w.x; acc[4].y += a1.x*w.y; acc[4].z += a1.x*w.z; acc[4].w += a1.x*w.w;
            acc[5].x += a1.y*w.x; acc[5].y += a1.y*w.y; acc[5].z += a1.y*w.z; acc[5].w += a1.y*w.w;
            acc[6].x += a1.z*w.x; acc[6].y += a1.z*w.y; acc[6].z += a1.z*w.z; acc[6].w += a1.z*w.w;
            acc[7].x += a1.w*w.x; acc[7].y += a1.w*w.y; acc[7].z += a1.w*w.z; acc[7].w += a1.w*w.w;
        }
        #pragma unroll
        for (int b = 0; b < BS; ++b)
            *(float4*)(lpart + ((size_t)blockIdx.y*8 + b)*V + v) = acc[b];
    } else if (nc > 0) {
        for (int ii = 0; ii < 256; ++ii) {
            for (int c = 0; c < nc; ++c) {
                float wv = Wout[(size_t)(r0+ii)*V + v + c];
                #pragma unroll
                for (int b = 0; b < BS; ++b) {
                    float a = tile[ii*8 + b];
                    float* ac = (float*)&acc[b];
                    ac[c] += a * wv;
                }
            }
        }
        for (int b = 0; b < BS; ++b) {
            const float* ac = (const float*)&acc[b];
            for (int c = 0; c < nc; ++c)
                lpart[((size_t)blockIdx.y*8 + b)*V + v + c] = ac[c];
        }
    }
}

#define TKCH 6283
__global__ __launch_bounds__(256) void k_topk_part(
    const float* __restrict__ lpart, const float* __restrict__ bout,
    float* __restrict__ cand_v, int* __restrict__ cand_i,
    float* __restrict__ cm, float* __restrict__ clp)
{
    int b = blockIdx.x, c = blockIdx.y, t = threadIdx.x;
    int vstart = c * TKCH;
    int vend = (vstart + TKCH < V) ? (vstart + TKCH) : V;
    float bv[8]; int bi[8];
    #pragma unroll
    for (int r = 0; r < 8; ++r) { bv[r] = -3.0e38f; bi[r] = 0x7fffffff; }
    float m = -3.0e38f, l = 0.f;
    for (int v = vstart + t; v < vend; v += 256) {
        float x = bout[v];
        #pragma unroll
        for (int r = 0; r < 8; ++r)
            x += lpart[((size_t)r*8 + b)*V + v];
        if (x > m) { l = l * expf(m - x) + 1.f; m = x; }
        else         l += expf(x - m);
        if (x > bv[7]) {
            bv[7] = x; bi[7] = v;
            #pragma unroll
            for (int q = 7; q > 0; --q) {
                if (bv[q] > bv[q-1]) {
                    float tv = bv[q]; bv[q] = bv[q-1]; bv[q-1] = tv;
                    int   ti = bi[q]; bi[q] = bi[q-1]; bi[q-1] = ti;
                }
            }
        }
    }
    __shared__ float pm[256], pl[256];
    pm[t] = m; pl[t] = l;
    __syncthreads();
    for (int off = 128; off; off >>= 1) {
        if (t < off) {
            float m2 = pm[t+off], l2 = pl[t+off];
            float M = fmaxf(pm[t], m2);
            pl[t] = pl[t]*expf(pm[t]-M) + l2*expf(m2-M);
            pm[t] = M;
        }
        __syncthreads();
    }
    if (t == 0) { cm[b*8 + c] = pm[0]; clp[b*8 + c] = pl[0]; }

    __shared__ float pv[2048];
    __shared__ int   pi[2048];
    __shared__ float rv[256];
    __shared__ int   ri[256], rp[256];
    #pragma unroll
    for (int r = 0; r < 8; ++r) { pv[t*8+r] = bv[r]; pi[t*8+r] = bi[r]; }
    __syncthreads();
    for (int round = 0; round < 8; ++round) {
        float lv = -3.0e38f; int li = 0x7fffffff, lp = -1;
        #pragma unroll
        for (int r = 0; r < 8; ++r) {
            float v2 = pv[t*8+r]; int i2 = pi[t*8+r];
            if (v2 > lv || (v2 == lv && i2 < li)) { lv = v2; li = i2; lp = t*8+r; }
        }
        rv[t] = lv; ri[t] = li; rp[t] = lp;
        __syncthreads();
        for (int off = 128; off; off >>= 1) {
            if (t < off) {
                if (rv[t+off] > rv[t] || (rv[t+off] == rv[t] && ri[t+off] < ri[t])) {
                    rv[t] = rv[t+off]; ri[t] = ri[t+off]; rp[t] = rp[t+off];
                }
            }
            __syncthreads();
        }
        if (t == 0) {
            cand_v[(b*8 + c)*8 + round] = rv[0];
            cand_i[(b*8 + c)*8 + round] = ri[0];
            pv[rp[0]] = -3.0e38f; pi[rp[0]] = 0x7fffffff;
        }
        __syncthreads();
    }
}

__global__ __launch_bounds__(256) void k_merge_update_fb(
    const float* __restrict__ cand_v, const int* __restrict__ cand_i,
    const float* __restrict__ cm, const float* __restrict__ clp,
    const float* cum_i, const int* len_i, const int* fin_i,
    const int* lat_i, const int* tok_i,
    float* cum_o, int* len_o, int* fin_o, int* lat_o, int* tok_o,
    const float* __restrict__ hcT, float* __restrict__ h, int step)
{
    int t = threadIdx.x;
    __shared__ float t8v[64];
    __shared__ int   t8i[64];
    __shared__ float lse[8];
    if (t < 8) {
        int b = t;
        float m = -3.0e38f, l = 0.f;
        for (int c = 0; c < 8; ++c) {
            float m2 = cm[b*8 + c], l2 = clp[b*8 + c];
            float M = fmaxf(m, m2);
            l = l*expf(m - M) + l2*expf(m2 - M);
            m = M;
        }
        lse[b] = m + logf(l);
        bool taken[64];
        for (int i = 0; i < 64; ++i) taken[i] = false;
        for (int round = 0; round < 8; ++round) {
            float bvv = -3.4e38f; int bii = 0x7fffffff, bp = 0;
            for (int i = 0; i < 64; ++i) {
                if (taken[i]) continue;
                float v2 = cand_v[b*64 + i]; int i2 = cand_i[b*64 + i];
                if (v2 > bvv || (v2 == bvv && i2 < bii)) { bvv = v2; bii = i2; bp = i; }
            }
            taken[bp] = true;
            t8v[b*8 + round] = bvv;
            t8i[b*8 + round] = bii;
        }
    }
    __syncthreads();

    __shared__ float flat[64];
    __shared__ float ccum[64];
    __shared__ int   clen[64];
    __shared__ int   sel[8];
    if (t < 64) {
        int b = t >> 3, j = t & 7;
        int alive = fin_i[b] ? 0 : 1;
        float lp = t8v[b*8 + j] - lse[b];
        float cc = cum_i[b] + (alive ? lp : 0.f);
        int   cln = len_i[b] + alive;
        float score = cc / (float)cln;
        bool valid = (alive || j == 0) && ((step > 0) || (b == 0));
        flat[t] = valid ? score : NEGV;
        ccum[t] = cc; clen[t] = cln;
    }
    __syncthreads();
    if (t == 0) {
        bool taken[64];
        for (int i = 0; i < 64; ++i) taken[i] = false;
        for (int r = 0; r < 8; ++r) {
            float bestv = -3.4e38f; int bidx = 0;
            for (int i = 0; i < 64; ++i) {
                if (!taken[i] && flat[i] > bestv) { bestv = flat[i]; bidx = i; }
            }
            taken[bidx] = true; sel[r] = bidx;
        }
    }
    __syncthreads();
    if (t < 8) {
        int idx = sel[t];
        int parent = idx >> 3, child = idx & 7;
        int p_fin = fin_i[parent];
        int new_tok = t8i[parent*8 + child];
        cum_o[t] = ccum[idx];
        len_o[t] = clen[idx];
        fin_o[t] = (p_fin || new_tok == EOS) ? 1 : 0;
        lat_o[t] = p_fin ? lat_i[parent] : new_tok;
    }
    __syncthreads();
    for (int m = t; m < BS*T; m += 256) {
        int nb = m / T, pos = m % T;
        int idx = sel[nb];
        int parent = idx >> 3, child = idx & 7;
        int p_fin = fin_i[parent];
        int p_len = len_i[parent];
        int new_tok = t8i[parent*8 + child];
        int val = tok_i[parent*T + pos];
        if (pos == p_len - 1 && !p_fin) val = new_tok;
        tok_o[m] = val;
    }
    for (int m = t; m < BS*H; m += 256) {
        int nb = m / H, j = m % H;
        int parent = sel[nb] >> 3;
        h[m] = hcT[(size_t)j*8 + parent];
    }
}

// ---------------- finalize ----------------
__global__ void k_final(const float* cum, const int* len, const int* fin,
                        const int* tok, float* out)
{
    int t = threadIdx.x;
    __shared__ int bestIdx;
    if (t == 0) {
        bool anyf = false;
        for (int b = 0; b < BS; ++b) anyf = anyf || (fin[b] != 0);
        float bestv = -3.4e38f; int bi_ = 0;
        for (int b = 0; b < BS; ++b) {
            float sc = cum[b] / (float)len[b];
            float adj = anyf ? (fin[b] ? sc : NEGV) : sc;
            if (adj > bestv) { bestv = adj; bi_ = b; }
        }
        bestIdx = bi_;
        out[T] = cum[bi_] / (float)len[bi_];
    }
    __syncthreads();
    if (t < T) out[t] = (float)tok[bestIdx*T + t];
}

extern "C" void kernel_launch(void* const* d_in, const int* in_sizes, int n_in,
                              void* d_out, int out_size, void* d_ws, size_t ws_size,
                              hipStream_t stream) {
    const float* emb  = (const float*)d_in[0];
    const float* Wx   = (const float*)d_in[1];
    const float* Wh   = (const float*)d_in[2];
    const float* Wout = (const float*)d_in[3];
    const float* bout = (const float*)d_in[4];
    const float* enc  = (const float*)d_in[5];
    const float* h0   = (const float*)d_in[6];
    float* out = (float*)d_out;

    bool big = ws_size >= (size_t)230*1024*1024;   // bf16 path needs ~209 MiB

    char* w = (char*)d_ws;
    auto alloc = [&](size_t bytes) -> char* {
        char* p = w; w += (bytes + 255) & ~(size_t)255; return p;
    };

    unsigned short* Wb = nullptr;
    if (big) Wb = (unsigned short*)alloc((size_t)2048*VP*2);   // 196.3 MiB, FIRST

    float* h      = (float*)alloc((size_t)BS*H*4);
    float* hcT    = (float*)alloc((size_t)2*H*BS*4);
    float* part   = (float*)alloc((size_t)KS*4*BS*H*4);        // 2 MiB
    float* cumb0  = (float*)alloc(8*4);
    float* cumb1  = (float*)alloc(8*4);
    int* lenb0 = (int*)alloc(8*4);
    int* lenb1 = (int*)alloc(8*4);
    int* finb0 = (int*)alloc(8*4);
    int* finb1 = (int*)alloc(8*4);
    int* latb0 = (int*)alloc(8*4);
    int* latb1 = (int*)alloc(8*4);
    int* tokb0 = (int*)alloc((size_t)BS*T*4);
    int* tokb1 = (int*)alloc((size_t)BS*T*4);

    // big-path buffers
    float* candV = nullptr; int* candI = nullptr;
    float* candM = nullptr; float* candL = nullptr;
    int* top24i = nullptr; float* exV = nullptr; float* lse8 = nullptr;
    // fallback buffers
    float* lpart = nullptr; float* cand_v = nullptr; int* cand_i = nullptr;
    float* cm = nullptr; float* clp = nullptr;

    if (big) {
        candV = (float*)alloc((size_t)8*NC24*4);
        candI = (int*)  alloc((size_t)8*NC24*4);
        candM = (float*)alloc((size_t)8*NSB*4);
        candL = (float*)alloc((size_t)8*NSB*4);
        top24i = (int*) alloc(8*24*4);
        exV   = (float*)alloc(8*24*4);
        lse8  = (float*)alloc(8*4);
    } else {
        lpart  = (float*)alloc((size_t)8*BS*V*4);
        cand_v = (float*)alloc(8*8*8*4);
        cand_i = (int*)  alloc(8*8*8*4);
        cm     = (float*)alloc(64*4);
        clp    = (float*)alloc(64*4);
    }

    float* cumb[2] = {cumb0, cumb1};
    int*   lenb[2] = {lenb0, lenb1};
    int*   finb[2] = {finb0, finb1};
    int*   latb[2] = {latb0, latb1};
    int*   tokb[2] = {tokb0, tokb1};

    k_init<<<1, 256, 0, stream>>>(h0, h, cumb[0], lenb[0], finb[0], latb[0], tokb[0]);
    if (big) k_cast<<<2048, 256, 0, stream>>>(Wout, Wb);

    for (int s = 0; s < T; ++s) {
        int p = s & 1, q = 1 - p;
        k_gru_part<<<dim3(4, KS), 256, 0, stream>>>(emb, Wx, Wh, h, latb[p], part);
        k_gate_attn<<<BS, 256, 0, stream>>>(part, h, enc, hcT);
        if (big) {
            k_screen<<<NSB, 256, 0, stream>>>(Wb, bout, hcT, candV, candI, candM, candL);
            k_merge24<<<BS, 64, 0, stream>>>(candV, candI, candM, candL, top24i, lse8);
            k_rescore<<<dim3(BS, 24), 256, 0, stream>>>(Wout, bout, hcT, top24i, exV);
            k_update<<<1, 256, 0, stream>>>(exV, top24i, lse8,
                                            cumb[p], lenb[p], finb[p], latb[p], tokb[p],
                                            cumb[q], lenb[q], finb[q], latb[q], tokb[q],
                                            hcT, h, s);
        } else {
            k_logits_part<<<dim3(50, 8), 256, 0, stream>>>(Wout, hcT, lpart);
            k_topk_part<<<dim3(BS, 8), 256, 0, stream>>>(lpart, bout, cand_v, cand_i, cm, clp);
            k_merge_update_fb<<<1, 256, 0, stream>>>(cand_v, cand_i, cm, clp,
                                                     cumb[p], lenb[p], finb[p], latb[p], tokb[p],
                                                     cumb[q], lenb[q], finb[q], latb[q], tokb[q],
                                                     hcT, h, s);
        }
    }
    k_final<<<1, 64, 0, stream>>>(cumb[0], lenb[0], finb[0], tokb[0], out);
}